// Round 1
// baseline (319.412 us; speedup 1.0000x reference)
//
#include <hip/hip_runtime.h>

// SSL2d: per-channel sub-pixel bilinear shift with zero padding.
// x: (B=32, C=384, H=56, W=56) fp32; a,b: (C,) fp32 shifts in ~[-1,1].
// out[n,c,h,w] = bilinear sample of x[n,c] at (h + a[c], w + b[c]).

constexpr int B = 32;
constexpr int C = 384;
constexpr int H = 56;
constexpr int W = 56;
constexpr int HW = H * W;
constexpr int TOTAL = B * C * HW;  // 38,535,168 < 2^31

__global__ __launch_bounds__(256) void ssl2d_kernel(
    const float* __restrict__ x,
    const float* __restrict__ a,
    const float* __restrict__ b,
    float* __restrict__ out) {
    int idx = blockIdx.x * 256 + threadIdx.x;
    if (idx >= TOTAL) return;

    // Decompose flat index. W, H, C are compile-time constants -> magic-mul.
    int w = idx % W;
    int t = idx / W;          // (n*C + c)*H + h
    int h = t % H;
    int nc = t / H;           // n*C + c
    int c = nc % C;

    // Per-channel shift params (wave-uniform within a channel; L1 broadcast).
    float ac = a[c];
    float bc = b[c];
    float iaf = floorf(ac);
    float ibf = floorf(bc);
    float fa = ac - iaf;      // fractional part along height
    float fb = bc - ibf;      // fractional part along width
    int ia = (int)iaf;
    int ib = (int)ibf;

    int hy0 = h + ia;
    int hy1 = hy0 + 1;
    int wx0 = w + ib;
    int wx1 = wx0 + 1;

    // Base of this (n,c) plane.
    const float* plane = x + (idx - h * W - w);

    bool vh0 = (unsigned)hy0 < (unsigned)H;
    bool vh1 = (unsigned)hy1 < (unsigned)H;
    bool vw0 = (unsigned)wx0 < (unsigned)W;
    bool vw1 = (unsigned)wx1 < (unsigned)W;

    int r0 = hy0 * W;
    int r1 = hy1 * W;

    float x00 = (vh0 && vw0) ? plane[r0 + wx0] : 0.0f;
    float x01 = (vh0 && vw1) ? plane[r0 + wx1] : 0.0f;
    float x10 = (vh1 && vw0) ? plane[r1 + wx0] : 0.0f;
    float x11 = (vh1 && vw1) ? plane[r1 + wx1] : 0.0f;

    float w00 = (1.0f - fa) * (1.0f - fb);
    float w01 = (1.0f - fa) * fb;
    float w10 = fa * (1.0f - fb);
    float w11 = fa * fb;

    out[idx] = w00 * x00 + w01 * x01 + w10 * x10 + w11 * x11;
}

extern "C" void kernel_launch(void* const* d_in, const int* in_sizes, int n_in,
                              void* d_out, int out_size, void* d_ws, size_t ws_size,
                              hipStream_t stream) {
    const float* x = (const float*)d_in[0];
    const float* a = (const float*)d_in[1];
    const float* b = (const float*)d_in[2];
    float* out = (float*)d_out;

    dim3 block(256);
    dim3 grid((TOTAL + 255) / 256);
    ssl2d_kernel<<<grid, block, 0, stream>>>(x, a, b, out);
}

// Round 2
// 280.080 us; speedup vs baseline: 1.1404x; 1.1404x over previous
//
#include <hip/hip_runtime.h>

// SSL2d: per-channel sub-pixel bilinear shift with zero padding.
// x: (B=32, C=384, H=56, W=56) fp32; a,b: (C,) fp32 shifts in ~[-1,1].
//
// Strategy: one block per (n,c) plane. Since a,b in [-1,1], floor in {-1,0},
// so sampling only touches rows/cols within +-1 of the plane.
// Phase A: horizontal lerp staged into LDS (rows hy=-1..56, zero-padded).
// Phase B: vertical lerp, float4 LDS reads + float4 stores.

constexpr int C  = 384;
constexpr int H  = 56;
constexpr int W  = 56;
constexpr int HW = H * W;        // 3136
constexpr int ROWS = H + 2;      // padded rows: hy = -1..56 stored at r_pad = hy+1
constexpr int NQ = HW / 4;       // 784 output float4s per plane
constexpr int QPR = W / 4;       // 14 quads per row

__global__ __launch_bounds__(256) void ssl2d_kernel(
    const float* __restrict__ x,
    const float* __restrict__ a,
    const float* __restrict__ b,
    float* __restrict__ out) {
    __shared__ float Lw[ROWS * W];   // 58*56*4 = 12992 B

    int nc = blockIdx.x;             // plane index = n*C + c
    int c = nc % C;
    const float* plane = x + nc * HW;

    // Per-channel params (block-uniform -> scalarized by compiler).
    float ac = a[c];
    float bc = b[c];
    float iaf = floorf(ac);
    float ibf = floorf(bc);
    float fa = ac - iaf;             // fractional shift along height
    float fb = bc - ibf;             // fractional shift along width
    int ia = (int)iaf;               // in {-1, 0}
    int ib = (int)ibf;               // in {-1, 0}

    int t = (int)threadIdx.x;
    int w = t & 63;                  // lane's column (56..63 idle)
    int rbase = t >> 6;              // wave id 0..3 -> starting padded row

    // ---- Phase A: Lw[r_pad][w] = (1-fb)*xm[hy][w+ib] + fb*xm[hy][w+ib+1]
    // where hy = r_pad-1, xm is zero outside [0,H)x[0,W).
    float fb1 = 1.0f - fb;
    for (int r_pad = rbase; r_pad < ROWS; r_pad += 4) {
        if (w < W) {
            int hy = r_pad - 1;
            float v = 0.0f;
            if ((unsigned)hy < (unsigned)H) {        // wave-uniform branch
                int c0 = w + ib;
                int c1 = c0 + 1;
                // clamp addresses (avoid OOB at buffer ends), mask values
                int c0c = min(max(c0, 0), W - 1);
                int c1c = min(max(c1, 0), W - 1);
                const float* row = plane + hy * W;
                float v0 = row[c0c];
                float v1 = row[c1c];
                v0 = ((unsigned)c0 < (unsigned)W) ? v0 : 0.0f;
                v1 = ((unsigned)c1 < (unsigned)W) ? v1 : 0.0f;
                v = fb1 * v0 + fb * v1;
            }
            Lw[r_pad * W + w] = v;
        }
    }
    __syncthreads();

    // ---- Phase B: out[h][w] = (1-fa)*Lw[h+ia+1][w] + fa*Lw[h+ia+2][w]
    float wa0 = 1.0f - fa;
    float wa1 = fa;
    float* outp = out + nc * HW;
    for (int q = t; q < NQ; q += 256) {
        int h  = q / QPR;            // const div -> magic mul
        int wq = (q - h * QPR) * 4;  // aligned quad column
        int rp = h + ia + 1;         // 0..56
        int base = rp * W + wq;      // multiple of 4 words -> 16B aligned
        float4 f0 = *(const float4*)(&Lw[base]);
        float4 f1 = *(const float4*)(&Lw[base + W]);
        float4 o;
        o.x = wa0 * f0.x + wa1 * f1.x;
        o.y = wa0 * f0.y + wa1 * f1.y;
        o.z = wa0 * f0.z + wa1 * f1.z;
        o.w = wa0 * f0.w + wa1 * f1.w;
        *(float4*)(&outp[q * 4]) = o;
    }
}

extern "C" void kernel_launch(void* const* d_in, const int* in_sizes, int n_in,
                              void* d_out, int out_size, void* d_ws, size_t ws_size,
                              hipStream_t stream) {
    const float* x = (const float*)d_in[0];
    const float* a = (const float*)d_in[1];
    const float* b = (const float*)d_in[2];
    float* out = (float*)d_out;

    int nplanes = out_size / HW;     // B*C = 12288
    ssl2d_kernel<<<dim3(nplanes), dim3(256), 0, stream>>>(x, a, b, out);
}

// Round 3
// 264.986 us; speedup vs baseline: 1.2054x; 1.0570x over previous
//
#include <hip/hip_runtime.h>

// SSL2d: per-channel sub-pixel bilinear shift with zero padding.
// x: (B=32, C=384, H=56, W=56) fp32; a,b: (C,) fp32 shifts in ~[-1,1]
// => floor(a), floor(b) in {-1, 0}: sampling touches only rows/cols +-1.
//
// One thread = one 2(rows) x 4(cols, aligned) output patch.
// 3 aligned float4 row loads + 3 scalar edge loads, all independent (no LDS,
// no barrier, no serial chain) -> latency hidden by MLP, not by staging.

constexpr int C  = 384;
constexpr int H  = 56;
constexpr int W  = 56;
constexpr int HW = H * W;     // 3136
constexpr int HP = H / 2;     // 28 row-pairs per plane
constexpr int QW = W / 4;     // 14 column-quads per row

__global__ __launch_bounds__(256) void ssl2d_kernel(
    const float* __restrict__ x,
    const float* __restrict__ a,
    const float* __restrict__ b,
    float* __restrict__ out,
    int total) {
    int q = blockIdx.x * 256 + (int)threadIdx.x;
    if (q >= total) return;

    // q -> (nc, hp, wq); consecutive lanes sweep wq then hp (coalesced).
    int wq = q % QW;
    int t  = q / QW;
    int hp = t % HP;
    int nc = t / HP;
    int c  = nc % C;

    // Per-channel params (channel-uniform across ~392 consecutive threads).
    float ac = a[c];
    float bc = b[c];
    float iaf = floorf(ac);
    float ibf = floorf(bc);
    float fa = ac - iaf;          // fractional shift along height
    float fb = bc - ibf;          // fractional shift along width
    int ia = (int)iaf;            // in {-1, 0}
    int ib = (int)ibf;            // in {-1, 0}

    const float* plane = x + nc * HW;
    int wb = wq * 4;              // aligned output column base
    int h2 = hp * 2;              // output row base

    // Source cols needed: wb+ib .. wb+ib+4 (5 cols). The aligned float4 at wb
    // covers 4 of them; one extra scalar at wb-1 (ib=-1) or wb+4 (ib=0).
    bool ib0 = (ib == 0);
    int ecol = ib0 ? (wb + 4) : (wb - 1);
    bool evalid = (unsigned)ecol < (unsigned)W;
    int ecolc = evalid ? ecol : 0;

    float fb1 = 1.0f - fb;
    int R0 = h2 + ia;             // first source row

    float hr[3][4];               // horizontally-lerped rows
#pragma unroll
    for (int r = 0; r < 3; ++r) {
        int hy = R0 + r;
        bool vrow = (unsigned)hy < (unsigned)H;
        const float* rowp = plane + (vrow ? hy : 0) * W;
        float4 f = *(const float4*)(rowp + wb);     // aligned, coalesced
        float  e = rowp[ecolc];
        e = evalid ? e : 0.0f;
        float v0 = ib0 ? f.x : e;
        float v1 = ib0 ? f.y : f.x;
        float v2 = ib0 ? f.z : f.y;
        float v3 = ib0 ? f.w : f.z;
        float v4 = ib0 ? e   : f.w;
        float m = vrow ? 1.0f : 0.0f;               // zero-pad OOB rows
        hr[r][0] = m * (fb1 * v0 + fb * v1);
        hr[r][1] = m * (fb1 * v1 + fb * v2);
        hr[r][2] = m * (fb1 * v2 + fb * v3);
        hr[r][3] = m * (fb1 * v3 + fb * v4);
    }

    float wa0 = 1.0f - fa;
    float wa1 = fa;
    float* op = out + nc * HW + h2 * W + wb;
    float4 o0, o1;
    o0.x = wa0 * hr[0][0] + wa1 * hr[1][0];
    o0.y = wa0 * hr[0][1] + wa1 * hr[1][1];
    o0.z = wa0 * hr[0][2] + wa1 * hr[1][2];
    o0.w = wa0 * hr[0][3] + wa1 * hr[1][3];
    o1.x = wa0 * hr[1][0] + wa1 * hr[2][0];
    o1.y = wa0 * hr[1][1] + wa1 * hr[2][1];
    o1.z = wa0 * hr[1][2] + wa1 * hr[2][2];
    o1.w = wa0 * hr[1][3] + wa1 * hr[2][3];
    *(float4*)op       = o0;
    *(float4*)(op + W) = o1;
}

extern "C" void kernel_launch(void* const* d_in, const int* in_sizes, int n_in,
                              void* d_out, int out_size, void* d_ws, size_t ws_size,
                              hipStream_t stream) {
    const float* x = (const float*)d_in[0];
    const float* a = (const float*)d_in[1];
    const float* b = (const float*)d_in[2];
    float* out = (float*)d_out;

    int nplanes = out_size / HW;          // B*C = 12288
    int total = nplanes * HP * QW;        // 4,816,896 patches
    int blocks = (total + 255) / 256;     // 18,816
    ssl2d_kernel<<<dim3(blocks), dim3(256), 0, stream>>>(x, a, b, out, total);
}